// Round 1
// baseline (324.590 us; speedup 1.0000x reference)
//
#include <hip/hip_runtime.h>
#include <hip/hip_bf16.h>

#define B_ 64
#define V_ 64
#define E_ 4032
#define HID_ 128
#define IN_ 32

typedef __attribute__((ext_vector_type(8))) __bf16 bf16x8;
typedef __attribute__((ext_vector_type(4))) float f32x4;
typedef __attribute__((ext_vector_type(8))) short short8;

__device__ __forceinline__ unsigned short f2bf_bits(float f) {
  unsigned int u = __builtin_bit_cast(unsigned int, f);
  u += 0x7FFFu + ((u >> 16) & 1u);   // round-to-nearest-even
  return (unsigned short)(u >> 16);
}
__device__ __forceinline__ __bf16 f2bf(float f) {
  return __builtin_bit_cast(__bf16, f2bf_bits(f));
}

// Kernel 1: per-node fc1 halves.
// h1r[it][b][v][h] = sum_j W1[it+1][h][j]    * x[b][v][j] + b1[it+1][h]
// h1s[it][b][v][h] = sum_j W1[it+1][h][32+j] * x[b][v][j]
__global__ void precompute_h1(const float* __restrict__ x,
                              const float* __restrict__ w1,
                              const float* __restrict__ b1,
                              float* __restrict__ h1r,
                              float* __restrict__ h1s) {
  const int bv = blockIdx.x;           // b*V_ + v
  const int h = threadIdx.x;           // 0..127
  __shared__ float xs[IN_];
  if (h < IN_) xs[h] = x[bv * IN_ + h];
  __syncthreads();
#pragma unroll
  for (int it = 0; it < 3; ++it) {
    const float* wr = w1 + ((it + 1) * HID_ + h) * (2 * IN_);
    float ar = b1[(it + 1) * HID_ + h];
    float as = 0.f;
#pragma unroll
    for (int j = 0; j < IN_; j += 4) {
      float4 w4 = *(const float4*)(wr + j);
      ar += w4.x * xs[j] + w4.y * xs[j + 1] + w4.z * xs[j + 2] + w4.w * xs[j + 3];
      float4 v4 = *(const float4*)(wr + IN_ + j);
      as += v4.x * xs[j] + v4.y * xs[j + 1] + v4.z * xs[j + 2] + v4.w * xs[j + 3];
    }
    h1r[(it * (B_ * V_) + bv) * HID_ + h] = ar;
    h1s[(it * (B_ * V_) + bv) * HID_ + h] = as;
  }
}

// Kernel 2: per (b, recv-node v) block. 256 threads = 4 waves.
// Edge rows e_local = 0..62 map to senders u = e_local<v ? e_local : e_local+1.
// Row 63 is a zero dummy. MFMA fc2 per type, epilogue (+b2, relu, *edgeweight),
// reduce over 64 edge rows -> agg[128] in LDS -> fused output MLP.
__global__ void __launch_bounds__(256)
decoder_main(const float* __restrict__ x,
             const float* __restrict__ edges,
             const float* __restrict__ w2,
             const float* __restrict__ b2,
             const float* __restrict__ fc1w,
             const float* __restrict__ fc1b,
             const float* __restrict__ fc2w,
             const float* __restrict__ fc2b,
             const float* __restrict__ muw,
             const float* __restrict__ mub,
             const float* __restrict__ h1r,
             const float* __restrict__ h1s,
             float* __restrict__ out) {
  const int v = blockIdx.x;
  const int b = blockIdx.y;
  const int t = threadIdx.x;
  const int wave = t >> 6;
  const int lane = t & 63;
  const int l15 = lane & 15;
  const int lg = lane >> 4;  // 0..3

  __shared__ __align__(16) unsigned short m1[64][136];  // bf16 bits, padded row
  __shared__ float ew[64];
  __shared__ float aggs[HID_];
  __shared__ float xs[IN_];
  __shared__ float p1[HID_];
  __shared__ float p2[HID_];

  if (t < IN_) xs[t] = x[(b * V_ + v) * IN_ + t];

  float outacc[4][2][4];
#pragma unroll
  for (int mt = 0; mt < 4; ++mt)
#pragma unroll
    for (int nt = 0; nt < 2; ++nt)
#pragma unroll
      for (int r = 0; r < 4; ++r) outacc[mt][nt][r] = 0.f;

  for (int it = 0; it < 3; ++it) {
    __syncthreads();  // protect m1/ew against previous iteration readers
    // ---- build m1 (bf16) : m1[e][k] = relu(h1r[v][k] + h1s[u][k]) ----
    {
      const int k0 = (t & 63) * 2;
      const float* hrp = h1r + ((it * B_ + b) * V_ + v) * HID_;
      const float hr0 = hrp[k0];
      const float hr1 = hrp[k0 + 1];
      const int ebase = wave;  // 0..3
#pragma unroll
      for (int j = 0; j < 16; ++j) {
        const int er = ebase + 4 * j;
        const bool valid = (er < 63);
        int u = (er < v) ? er : er + 1;
        if (!valid) u = v;  // safe dummy read
        const float* hsp = h1s + ((it * B_ + b) * V_ + u) * HID_;
        float v0 = fmaxf(hr0 + hsp[k0], 0.f);
        float v1 = fmaxf(hr1 + hsp[k0 + 1], 0.f);
        if (!valid) { v0 = 0.f; v1 = 0.f; }
        m1[er][k0] = f2bf_bits(v0);
        m1[er][k0 + 1] = f2bf_bits(v1);
      }
      if (t < 64) {
        float w = 0.f;
        if (t < 63) {
          const int u = (t < v) ? t : t + 1;
          const int e = u * 63 + ((v > u) ? (v - 1) : v);
          w = edges[(b * E_ + e) * 4 + (it + 1)];
        }
        ew[t] = w;
      }
    }
    // ---- load B fragments (W2^T columns -> bf16), reg-resident ----
    const float* w2t = w2 + (it + 1) * HID_ * HID_;
    bf16x8 bfrag[2][4];
#pragma unroll
    for (int nt = 0; nt < 2; ++nt) {
      const int h = wave * 32 + nt * 16 + l15;
#pragma unroll
      for (int ks = 0; ks < 4; ++ks) {
        const int k0 = ks * 32 + lg * 8;
        const float* p = w2t + h * HID_ + k0;
        float4 a = *(const float4*)p;
        float4 c = *(const float4*)(p + 4);
        bf16x8 fr;
        fr[0] = f2bf(a.x); fr[1] = f2bf(a.y); fr[2] = f2bf(a.z); fr[3] = f2bf(a.w);
        fr[4] = f2bf(c.x); fr[5] = f2bf(c.y); fr[6] = f2bf(c.z); fr[7] = f2bf(c.w);
        bfrag[nt][ks] = fr;
      }
    }
    float b2v[2];
#pragma unroll
    for (int nt = 0; nt < 2; ++nt)
      b2v[nt] = b2[(it + 1) * HID_ + wave * 32 + nt * 16 + l15];
    __syncthreads();

    // ---- MFMA: out[e][h] over 64 edges x 32 h (per wave) x K=128 ----
#pragma unroll
    for (int mt = 0; mt < 4; ++mt) {
      bf16x8 af[4];
#pragma unroll
      for (int ks = 0; ks < 4; ++ks) {
        const unsigned short* ap = &m1[mt * 16 + l15][ks * 32 + lg * 8];
        af[ks] = __builtin_bit_cast(bf16x8, *(const short8*)ap);
      }
#pragma unroll
      for (int nt = 0; nt < 2; ++nt) {
        f32x4 macc = {0.f, 0.f, 0.f, 0.f};
#pragma unroll
        for (int ks = 0; ks < 4; ++ks)
          macc = __builtin_amdgcn_mfma_f32_16x16x32_bf16(af[ks], bfrag[nt][ks], macc, 0, 0, 0);
#pragma unroll
        for (int r = 0; r < 4; ++r) {
          float val = fmaxf(macc[r] + b2v[nt], 0.f);
          val *= ew[mt * 16 + lg * 4 + r];
          outacc[mt][nt][r] += val;
        }
      }
    }
  }

  // ---- reduce over 64 edge rows -> agg ----
#pragma unroll
  for (int nt = 0; nt < 2; ++nt) {
    float s = 0.f;
#pragma unroll
    for (int mt = 0; mt < 4; ++mt)
#pragma unroll
      for (int r = 0; r < 4; ++r) s += outacc[mt][nt][r];
    s += __shfl_xor(s, 16);
    s += __shfl_xor(s, 32);
    if (lane < 16) aggs[wave * 32 + nt * 16 + l15] = s;
  }
  __syncthreads();

  // ---- fused output MLP (fp32) ----
  if (t < HID_) {
    float acc = fc1b[t];
    const float* wr = fc1w + t * (IN_ + HID_);
#pragma unroll
    for (int j = 0; j < IN_; j += 4) {
      float4 w4 = *(const float4*)(wr + j);
      acc += w4.x * xs[j] + w4.y * xs[j + 1] + w4.z * xs[j + 2] + w4.w * xs[j + 3];
    }
#pragma unroll
    for (int j = 0; j < HID_; j += 4) {
      float4 w4 = *(const float4*)(wr + IN_ + j);
      acc += w4.x * aggs[j] + w4.y * aggs[j + 1] + w4.z * aggs[j + 2] + w4.w * aggs[j + 3];
    }
    p1[t] = fmaxf(acc, 0.f);
  }
  __syncthreads();
  if (t < HID_) {
    float acc = fc2b[t];
    const float* wr = fc2w + t * HID_;
#pragma unroll
    for (int j = 0; j < HID_; j += 4) {
      float4 w4 = *(const float4*)(wr + j);
      acc += w4.x * p1[j] + w4.y * p1[j + 1] + w4.z * p1[j + 2] + w4.w * p1[j + 3];
    }
    p2[t] = fmaxf(acc, 0.f);
  }
  __syncthreads();
  if (t < IN_) {
    float acc = mub[t];
    const float* wr = muw + t * HID_;
#pragma unroll
    for (int k = 0; k < HID_; k += 4) {
      float4 w4 = *(const float4*)(wr + k);
      acc += w4.x * p2[k] + w4.y * p2[k + 1] + w4.z * p2[k + 2] + w4.w * p2[k + 3];
    }
    out[(b * V_ + v) * IN_ + t] = xs[t] + acc;
  }
}

extern "C" void kernel_launch(void* const* d_in, const int* in_sizes, int n_in,
                              void* d_out, int out_size, void* d_ws, size_t ws_size,
                              hipStream_t stream) {
  const float* x     = (const float*)d_in[0];
  const float* edges = (const float*)d_in[1];
  const float* w1    = (const float*)d_in[2];
  const float* b1    = (const float*)d_in[3];
  const float* w2    = (const float*)d_in[4];
  const float* b2    = (const float*)d_in[5];
  const float* fc1w  = (const float*)d_in[6];
  const float* fc1b  = (const float*)d_in[7];
  const float* fc2w  = (const float*)d_in[8];
  const float* fc2b  = (const float*)d_in[9];
  const float* muw   = (const float*)d_in[10];
  const float* mub   = (const float*)d_in[11];
  float* out = (float*)d_out;

  float* h1r = (float*)d_ws;                       // 3*B*V*128 floats
  float* h1s = h1r + 3 * B_ * V_ * HID_;           // 3*B*V*128 floats

  precompute_h1<<<B_ * V_, 128, 0, stream>>>(x, w1, b1, h1r, h1s);
  decoder_main<<<dim3(V_, B_), 256, 0, stream>>>(x, edges, w2, b2, fc1w, fc1b,
                                                 fc2w, fc2b, muw, mub, h1r, h1s, out);
}

// Round 2
// 271.711 us; speedup vs baseline: 1.1946x; 1.1946x over previous
//
#include <hip/hip_runtime.h>
#include <hip/hip_bf16.h>

#define B_ 64
#define V_ 64
#define E_ 4032
#define HID_ 128
#define IN_ 32

typedef __attribute__((ext_vector_type(8))) __bf16 bf16x8;
typedef __attribute__((ext_vector_type(4))) float f32x4;
typedef __attribute__((ext_vector_type(8))) short short8;

__device__ __forceinline__ unsigned short f2bf_bits(float f) {
  unsigned int u = __builtin_bit_cast(unsigned int, f);
  u += 0x7FFFu + ((u >> 16) & 1u);   // round-to-nearest-even
  return (unsigned short)(u >> 16);
}

// ---------------- Kernel 1: h1 halves (fp32) + W2 -> bf16 ----------------
// 256 blocks x 256 threads; block handles 16 (b,v) nodes.
// h1r[tt][node][h] = b1[tt+1][h] + sum_j W1[tt+1][h][j]    * x[node][j]
// h1s[tt][node][h] =               sum_j W1[tt+1][h][32+j] * x[node][j]
__global__ void __launch_bounds__(256) precompute_k(
    const float* __restrict__ x, const float* __restrict__ w1,
    const float* __restrict__ b1, const float* __restrict__ w2,
    float* __restrict__ h1r, float* __restrict__ h1s,
    unsigned short* __restrict__ w2b) {
  const int bid = blockIdx.x;
  const int t = threadIdx.x;
  __shared__ float xs[16][IN_];
  for (int i = t; i < 16 * IN_; i += 256) xs[i >> 5][i & 31] = x[bid * 16 * IN_ + i];
  // W2 (types 1..3, 49152 elems) -> bf16: 192 elems per block
  if (t < 192) {
    const int idx = bid * 192 + t;
    w2b[idx] = f2bf_bits(w2[HID_ * HID_ + idx]);
  }
  __syncthreads();
  const int h = t & 127;
  const int half = t >> 7;
#pragma unroll
  for (int tt = 0; tt < 3; ++tt) {
    const float* wrow = w1 + ((tt + 1) * HID_ + h) * (2 * IN_) + half * IN_;
    float4 w[8];
#pragma unroll
    for (int j = 0; j < 8; ++j) w[j] = ((const float4*)wrow)[j];
    const float bias = half ? 0.f : b1[(tt + 1) * HID_ + h];
    float* dst = (half ? h1s : h1r) + ((size_t)tt * (B_ * V_) + bid * 16) * HID_ + h;
#pragma unroll
    for (int n = 0; n < 16; ++n) {
      float acc = bias;
#pragma unroll
      for (int j = 0; j < 8; ++j)
        acc += w[j].x * xs[n][4 * j] + w[j].y * xs[n][4 * j + 1] +
               w[j].z * xs[n][4 * j + 2] + w[j].w * xs[n][4 * j + 3];
      dst[n * HID_] = acc;  // lanes -> consecutive h: coalesced
    }
  }
}

// ---------------- Kernel 2: per (b, v) block, 256 thr = 4 waves ----------------
// m1 LDS layout is FRAGMENT-ORDER: slot s = mt*256 + ks*64 + lg*16 + l15 (16B units)
// -> every wave ds_write/ds_read is 64-lane contiguous 1KB (conflict-free).
__global__ void __launch_bounds__(256, 3)
decoder_main(const float* __restrict__ x, const float* __restrict__ edges,
             const float* __restrict__ b2, const float* __restrict__ fc1w,
             const float* __restrict__ fc1b, const float* __restrict__ fc2w,
             const float* __restrict__ fc2b, const float* __restrict__ muw,
             const float* __restrict__ mub, const float* __restrict__ h1r,
             const float* __restrict__ h1s, const unsigned short* __restrict__ w2b,
             float* __restrict__ out) {
  const int v = blockIdx.x;
  const int b = blockIdx.y;
  const int t = threadIdx.x;
  const int wave = t >> 6;
  const int lane = t & 63;
  const int l15 = lane & 15;
  const int lg = lane >> 4;

  __shared__ __align__(16) unsigned short m1[3 * 8192];  // 48KB, 3 types
  __shared__ float ew[3 * 64];
  __shared__ float aggs[HID_];
  __shared__ float xs[IN_];
  __shared__ float p1[HID_];
  __shared__ float p2[HID_];

  if (t < IN_) xs[t] = x[(b * V_ + v) * IN_ + t];

  // edge weights: waves 0..2 handle one type each
  if (wave < 3) {
    float wgt = 0.f;
    if (lane < 63) {
      const int uu = (lane < v) ? lane : lane + 1;
      const int eg = uu * 63 + ((v > uu) ? (v - 1) : v);
      wgt = edges[(b * E_ + eg) * 4 + wave + 1];
    }
    ew[wave * 64 + lane] = wgt;
  }

  // ---- build phase: each wave builds its own 16 edge rows (mt = wave) ----
  const int e_loc = wave * 16 + l15;
  int u = (e_loc < v) ? e_loc : e_loc + 1;
  if (e_loc >= 63) u = v;  // dummy row 63 (ew=0); safe finite read
#pragma unroll
  for (int tt = 0; tt < 3; ++tt) {
    const float* hr = h1r + ((size_t)(tt * B_ + b) * V_ + v) * HID_ + lg * 8;
    const float* hs = h1s + ((size_t)(tt * B_ + b) * V_ + u) * HID_ + lg * 8;
#pragma unroll
    for (int ks = 0; ks < 4; ++ks) {
      float4 ra = *(const float4*)(hr + ks * 32);
      float4 rb = *(const float4*)(hr + ks * 32 + 4);
      float4 sa = *(const float4*)(hs + ks * 32);
      float4 sb = *(const float4*)(hs + ks * 32 + 4);
      unsigned short o[8];
      o[0] = f2bf_bits(fmaxf(ra.x + sa.x, 0.f));
      o[1] = f2bf_bits(fmaxf(ra.y + sa.y, 0.f));
      o[2] = f2bf_bits(fmaxf(ra.z + sa.z, 0.f));
      o[3] = f2bf_bits(fmaxf(ra.w + sa.w, 0.f));
      o[4] = f2bf_bits(fmaxf(rb.x + sb.x, 0.f));
      o[5] = f2bf_bits(fmaxf(rb.y + sb.y, 0.f));
      o[6] = f2bf_bits(fmaxf(rb.z + sb.z, 0.f));
      o[7] = f2bf_bits(fmaxf(rb.w + sb.w, 0.f));
      // slot: mt=wave -> wave-contiguous 1KB write
      short8* dst = (short8*)&m1[tt * 8192 + ((wave * 4 + ks) * 64 + lane) * 8];
      *dst = *(const short8*)o;
    }
  }
  __syncthreads();  // the ONLY barrier before MFMA

  // ---- MFMA phase: 96 MFMAs per wave, epilogue fused ----
  float acc[4][2][4];
#pragma unroll
  for (int mt = 0; mt < 4; ++mt)
#pragma unroll
    for (int nt = 0; nt < 2; ++nt)
#pragma unroll
      for (int r = 0; r < 4; ++r) acc[mt][nt][r] = 0.f;

#pragma unroll
  for (int tt = 0; tt < 3; ++tt) {
    bf16x8 bfrag[2][4];
    float b2v[2];
#pragma unroll
    for (int nt = 0; nt < 2; ++nt) {
      const int h = wave * 32 + nt * 16 + l15;
#pragma unroll
      for (int ks = 0; ks < 4; ++ks)
        bfrag[nt][ks] = *(const bf16x8*)(w2b + ((size_t)(tt * HID_ + h)) * HID_ + ks * 32 + lg * 8);
      b2v[nt] = b2[(tt + 1) * HID_ + h];
    }
#pragma unroll
    for (int mt = 0; mt < 4; ++mt) {
      bf16x8 af[4];
#pragma unroll
      for (int ks = 0; ks < 4; ++ks)
        af[ks] = *(const bf16x8*)&m1[tt * 8192 + ((mt * 4 + ks) * 64 + lane) * 8];
#pragma unroll
      for (int nt = 0; nt < 2; ++nt) {
        f32x4 macc = {0.f, 0.f, 0.f, 0.f};
#pragma unroll
        for (int ks = 0; ks < 4; ++ks)
          macc = __builtin_amdgcn_mfma_f32_16x16x32_bf16(af[ks], bfrag[nt][ks], macc, 0, 0, 0);
#pragma unroll
        for (int r = 0; r < 4; ++r)
          acc[mt][nt][r] += fmaxf(macc[r] + b2v[nt], 0.f) * ew[tt * 64 + mt * 16 + lg * 4 + r];
      }
    }
  }

  // ---- reduce 64 edge rows -> agg[128] ----
#pragma unroll
  for (int nt = 0; nt < 2; ++nt) {
    float s = 0.f;
#pragma unroll
    for (int mt = 0; mt < 4; ++mt)
#pragma unroll
      for (int r = 0; r < 4; ++r) s += acc[mt][nt][r];
    s += __shfl_xor(s, 16);
    s += __shfl_xor(s, 32);
    if (lane < 16) aggs[wave * 32 + nt * 16 + l15] = s;
  }
  __syncthreads();

  // ---- fused output MLP (fp32) ----
  if (t < HID_) {
    float acc1 = fc1b[t];
    const float* wr = fc1w + t * (IN_ + HID_);
#pragma unroll
    for (int j = 0; j < IN_; j += 4) {
      float4 w4 = *(const float4*)(wr + j);
      acc1 += w4.x * xs[j] + w4.y * xs[j + 1] + w4.z * xs[j + 2] + w4.w * xs[j + 3];
    }
#pragma unroll
    for (int j = 0; j < HID_; j += 4) {
      float4 w4 = *(const float4*)(wr + IN_ + j);
      acc1 += w4.x * aggs[j] + w4.y * aggs[j + 1] + w4.z * aggs[j + 2] + w4.w * aggs[j + 3];
    }
    p1[t] = fmaxf(acc1, 0.f);
  }
  __syncthreads();
  if (t < HID_) {
    float acc2 = fc2b[t];
    const float* wr = fc2w + t * HID_;
#pragma unroll
    for (int j = 0; j < HID_; j += 4) {
      float4 w4 = *(const float4*)(wr + j);
      acc2 += w4.x * p1[j] + w4.y * p1[j + 1] + w4.z * p1[j + 2] + w4.w * p1[j + 3];
    }
    p2[t] = fmaxf(acc2, 0.f);
  }
  __syncthreads();
  if (t < IN_) {
    float accm = mub[t];
    const float* wr = muw + t * HID_;
#pragma unroll
    for (int k = 0; k < HID_; k += 4) {
      float4 w4 = *(const float4*)(wr + k);
      accm += w4.x * p2[k] + w4.y * p2[k + 1] + w4.z * p2[k + 2] + w4.w * p2[k + 3];
    }
    out[(b * V_ + v) * IN_ + t] = xs[t] + accm;
  }
}

extern "C" void kernel_launch(void* const* d_in, const int* in_sizes, int n_in,
                              void* d_out, int out_size, void* d_ws, size_t ws_size,
                              hipStream_t stream) {
  const float* x     = (const float*)d_in[0];
  const float* edges = (const float*)d_in[1];
  const float* w1    = (const float*)d_in[2];
  const float* b1    = (const float*)d_in[3];
  const float* w2    = (const float*)d_in[4];
  const float* b2    = (const float*)d_in[5];
  const float* fc1w  = (const float*)d_in[6];
  const float* fc1b  = (const float*)d_in[7];
  const float* fc2w  = (const float*)d_in[8];
  const float* fc2b  = (const float*)d_in[9];
  const float* muw   = (const float*)d_in[10];
  const float* mub   = (const float*)d_in[11];
  float* out = (float*)d_out;

  float* h1r = (float*)d_ws;                           // 3*4096*128 f32
  float* h1s = h1r + 3 * (B_ * V_) * HID_;             // 3*4096*128 f32
  unsigned short* w2b = (unsigned short*)(h1s + 3 * (B_ * V_) * HID_);  // 3*128*128 bf16

  precompute_k<<<256, 256, 0, stream>>>(x, w1, b1, w2, h1r, h1s, w2b);
  decoder_main<<<dim3(V_, B_), 256, 0, stream>>>(x, edges, b2, fc1w, fc1b, fc2w,
                                                 fc2b, muw, mub, h1r, h1s, w2b, out);
}

// Round 4
// 185.883 us; speedup vs baseline: 1.7462x; 1.4617x over previous
//
#include <hip/hip_runtime.h>
#include <hip/hip_bf16.h>

#define B_ 64
#define V_ 64
#define E_ 4032
#define HID_ 128
#define IN_ 32

typedef __attribute__((ext_vector_type(8))) __bf16 bf16x8;
typedef __attribute__((ext_vector_type(4))) __bf16 bf16x4;
typedef __attribute__((ext_vector_type(4))) float f32x4;

// ---------- Kernel 1a: per-node fc1 halves (fp32), 2 nodes/block ----------
__global__ void __launch_bounds__(256) node_h1(
    const float* __restrict__ x, const float* __restrict__ w1,
    const float* __restrict__ b1, float* __restrict__ h1r,
    float* __restrict__ h1s) {
  const int bid = blockIdx.x, t = threadIdx.x;
  const int h = t & 127, half = t >> 7;
  __shared__ float xs[2][IN_];
  if (t < 64) xs[t >> 5][t & 31] = x[bid * 64 + t];
  __syncthreads();
#pragma unroll
  for (int tt = 0; tt < 3; ++tt) {
    const float* wrow = w1 + ((size_t)((tt + 1) * HID_ + h)) * (2 * IN_) + half * IN_;
    float4 w[8];
#pragma unroll
    for (int j = 0; j < 8; ++j) w[j] = ((const float4*)wrow)[j];
    const float bias = half ? 0.f : b1[(tt + 1) * HID_ + h];
    float* dst = (half ? h1s : h1r) + ((size_t)tt * (B_ * V_) + bid * 2) * HID_ + h;
#pragma unroll
    for (int n = 0; n < 2; ++n) {
      float acc = bias;
#pragma unroll
      for (int j = 0; j < 8; ++j)
        acc += w[j].x * xs[n][4 * j] + w[j].y * xs[n][4 * j + 1] +
               w[j].z * xs[n][4 * j + 2] + w[j].w * xs[n][4 * j + 3];
      dst[n * HID_] = acc;  // coalesced over h
    }
  }
}

// ---------- Kernel 1b: weight prep (W2->bf16 fragment order; transposes) ----------
__global__ void __launch_bounds__(256) weight_prep(
    const float* __restrict__ w2, const float* __restrict__ fc1w,
    const float* __restrict__ fc2w, const float* __restrict__ muw,
    unsigned short* __restrict__ w2f, float* __restrict__ fc1wT,
    float* __restrict__ fc2wT, float* __restrict__ muwT) {
  const int i = blockIdx.x * 256 + threadIdx.x;
  if (i < 49152) {
    // dst idx = ((((tt*4+w)*2+nt)*4+ks)*64+lane)*8+e
    const int e = i & 7, lane = (i >> 3) & 63, ks = (i >> 9) & 3;
    const int nt = (i >> 11) & 1, w = (i >> 12) & 3, tt = i >> 14;
    const int o = w * 32 + nt * 16 + (lane & 15);
    const int k = ks * 32 + (lane >> 4) * 8 + e;
    w2f[i] = __builtin_bit_cast(unsigned short,
                                (__bf16)w2[((size_t)((tt + 1) * HID_ + o)) * HID_ + k]);
    return;
  }
  int j = i - 49152;
  if (j < 20480) { fc1wT[j] = fc1w[(j & 127) * (IN_ + HID_) + (j >> 7)]; return; }
  j -= 20480;
  if (j < 16384) { fc2wT[j] = fc2w[(j & 127) * HID_ + (j >> 7)]; return; }
  j -= 16384;
  if (j < 4096) { muwT[j] = muw[(j & 31) * HID_ + (j >> 5)]; }
}

// ---------- Kernel 2: per (b,v) edge-MFMA + aggregate ----------
// m1: row-major [64][128] bf16 per buffer, XOR-swizzled (byte ^= (row&7)<<4).
// Build loads are row-contiguous (coalesced); double-buffered over types.
__global__ void __launch_bounds__(256)
edge_mfma(const float* __restrict__ edges, const float* __restrict__ b2,
          const float* __restrict__ h1r, const float* __restrict__ h1s,
          const unsigned short* __restrict__ w2f, float* __restrict__ aggout) {
  const int v = blockIdx.x, b = blockIdx.y, t = threadIdx.x;
  const int wave = t >> 6, lane = t & 63;
  const int l15 = lane & 15, lg = lane >> 4;
  const int kq = lane & 31, rpar = lane >> 5;

  __shared__ __align__(16) unsigned short m1[2][64 * HID_];
  __shared__ float ew[3 * 64];

  if (wave < 3) {
    float wgt = 0.f;
    if (lane < 63) {
      const int uu = (lane < v) ? lane : lane + 1;
      const int eg = uu * 63 + ((v > uu) ? (v - 1) : v);
      wgt = edges[(b * E_ + eg) * 4 + wave + 1];
    }
    ew[wave * 64 + lane] = wgt;
  }

  // build type 0 into buf 0 (each wave builds rows 16w..16w+15, coalesced)
  {
    float4 hr = *(const float4*)(h1r + ((size_t)b * V_ + v) * HID_ + kq * 4);
#pragma unroll
    for (int j = 0; j < 8; ++j) {
      const int r = wave * 16 + j * 2 + rpar;
      int u = (r < v) ? r : r + 1;
      if (r == 63) u = v;
      float4 hs = *(const float4*)(h1s + ((size_t)b * V_ + u) * HID_ + kq * 4);
      bf16x4 pk;
      pk[0] = (__bf16)fmaxf(hr.x + hs.x, 0.f);
      pk[1] = (__bf16)fmaxf(hr.y + hs.y, 0.f);
      pk[2] = (__bf16)fmaxf(hr.z + hs.z, 0.f);
      pk[3] = (__bf16)fmaxf(hr.w + hs.w, 0.f);
      *(bf16x4*)((char*)m1[0] + r * 256 + ((kq * 8) ^ ((r & 7) << 4))) = pk;
    }
  }

  // B fragments for type 0 (coalesced 1KB per wave per (nt,ks))
  bf16x8 bfrag[2][4];
  float b2r[2];
#pragma unroll
  for (int nt = 0; nt < 2; ++nt) {
#pragma unroll
    for (int ks = 0; ks < 4; ++ks)
      bfrag[nt][ks] = *(const bf16x8*)(w2f + (((wave * 2 + nt) * 4 + ks) * 64 + lane) * 8);
    b2r[nt] = b2[HID_ + wave * 32 + nt * 16 + l15];
  }

  float acc[4][2][4];
#pragma unroll
  for (int mt = 0; mt < 4; ++mt)
#pragma unroll
    for (int nt = 0; nt < 2; ++nt)
#pragma unroll
      for (int r = 0; r < 4; ++r) acc[mt][nt][r] = 0.f;

  __syncthreads();

#pragma unroll
  for (int tt = 0; tt < 3; ++tt) {
    // prefetch next type's h1 rows into regs (overlaps with MFMA below)
    float4 hrn, hsn[8];
    if (tt < 2) {
      hrn = *(const float4*)(h1r + ((size_t)((tt + 1) * B_ + b) * V_ + v) * HID_ + kq * 4);
#pragma unroll
      for (int j = 0; j < 8; ++j) {
        const int r = wave * 16 + j * 2 + rpar;
        int u = (r < v) ? r : r + 1;
        if (r == 63) u = v;
        hsn[j] = *(const float4*)(h1s + ((size_t)((tt + 1) * B_ + b) * V_ + u) * HID_ + kq * 4);
      }
    }
    // MFMA on buffer tt&1
    const unsigned short* mb = m1[tt & 1];
#pragma unroll
    for (int mt = 0; mt < 4; ++mt) {
      bf16x8 af[4];
#pragma unroll
      for (int ks = 0; ks < 4; ++ks) {
        const int row = mt * 16 + l15;
        af[ks] = *(const bf16x8*)((const char*)mb + row * 256 +
                                  ((ks * 64 + lg * 16) ^ ((row & 7) << 4)));
      }
#pragma unroll
      for (int nt = 0; nt < 2; ++nt) {
        f32x4 macc = {0.f, 0.f, 0.f, 0.f};
#pragma unroll
        for (int ks = 0; ks < 4; ++ks)
          macc = __builtin_amdgcn_mfma_f32_16x16x32_bf16(af[ks], bfrag[nt][ks], macc, 0, 0, 0);
#pragma unroll
        for (int r = 0; r < 4; ++r)
          acc[mt][nt][r] += fmaxf(macc[r] + b2r[nt], 0.f) * ew[tt * 64 + mt * 16 + lg * 4 + r];
      }
    }
    // stage next type into the other buffer; reload bfrag
    if (tt < 2) {
#pragma unroll
      for (int j = 0; j < 8; ++j) {
        const int r = wave * 16 + j * 2 + rpar;
        bf16x4 pk;
        pk[0] = (__bf16)fmaxf(hrn.x + hsn[j].x, 0.f);
        pk[1] = (__bf16)fmaxf(hrn.y + hsn[j].y, 0.f);
        pk[2] = (__bf16)fmaxf(hrn.z + hsn[j].z, 0.f);
        pk[3] = (__bf16)fmaxf(hrn.w + hsn[j].w, 0.f);
        *(bf16x4*)((char*)m1[(tt + 1) & 1] + r * 256 + ((kq * 8) ^ ((r & 7) << 4))) = pk;
      }
#pragma unroll
      for (int nt = 0; nt < 2; ++nt) {
#pragma unroll
        for (int ks = 0; ks < 4; ++ks)
          bfrag[nt][ks] = *(const bf16x8*)(
              w2f + (((((tt + 1) * 4 + wave) * 2 + nt) * 4 + ks) * 64 + lane) * 8);
        b2r[nt] = b2[(tt + 2) * HID_ + wave * 32 + nt * 16 + l15];
      }
    }
    __syncthreads();
  }

  // reduce 64 edge rows -> agg, store coalesced-ish (64B per 16 lanes)
#pragma unroll
  for (int nt = 0; nt < 2; ++nt) {
    float s = 0.f;
#pragma unroll
    for (int mt = 0; mt < 4; ++mt)
#pragma unroll
      for (int r = 0; r < 4; ++r) s += acc[mt][nt][r];
    s += __shfl_xor(s, 16);
    s += __shfl_xor(s, 32);
    if (lane < 16)
      aggout[((size_t)b * V_ + v) * HID_ + wave * 32 + nt * 16 + l15] = s;
  }
}

// ---------- Kernel 3: output MLP (fp32), 8 nodes/block ----------
// Transposed weights: wave-uniform global reads (L1 broadcast), LDS broadcast
// for activations; no scattered loads anywhere.
__global__ void __launch_bounds__(256) out_mlp(
    const float* __restrict__ x, const float* __restrict__ aggout,
    const float* __restrict__ fc1wT, const float* __restrict__ fc1b,
    const float* __restrict__ fc2wT, const float* __restrict__ fc2b,
    const float* __restrict__ muwT, const float* __restrict__ mub,
    float* __restrict__ out) {
  const int t = threadIdx.x;
  const int g = t >> 5, j = t & 31;
  const int nodebase = blockIdx.x * 8;
  __shared__ float aug[8][160];
  __shared__ float p1[8][HID_];
  __shared__ float p2[8][HID_];

  aug[t >> 5][t & 31] = x[nodebase * IN_ + t];
  {
    float4 a4 = *(const float4*)(aggout + (size_t)nodebase * HID_ + t * 4);
    *(float4*)&aug[t >> 5][IN_ + (t & 31) * 4] = a4;
  }
  __syncthreads();

  // fc1: lane j owns output cols [4j, 4j+4)
  float4 a1 = *(const float4*)(fc1b + j * 4);
#pragma unroll 4
  for (int k = 0; k < IN_ + HID_; ++k) {
    float4 w = *(const float4*)(fc1wT + (size_t)k * HID_ + j * 4);
    const float a = aug[g][k];
    a1.x += w.x * a; a1.y += w.y * a; a1.z += w.z * a; a1.w += w.w * a;
  }
  a1.x = fmaxf(a1.x, 0.f); a1.y = fmaxf(a1.y, 0.f);
  a1.z = fmaxf(a1.z, 0.f); a1.w = fmaxf(a1.w, 0.f);
  *(float4*)&p1[g][j * 4] = a1;
  __syncthreads();

  float4 a2 = *(const float4*)(fc2b + j * 4);
#pragma unroll 4
  for (int k = 0; k < HID_; ++k) {
    float4 w = *(const float4*)(fc2wT + (size_t)k * HID_ + j * 4);
    const float a = p1[g][k];
    a2.x += w.x * a; a2.y += w.y * a; a2.z += w.z * a; a2.w += w.w * a;
  }
  a2.x = fmaxf(a2.x, 0.f); a2.y = fmaxf(a2.y, 0.f);
  a2.z = fmaxf(a2.z, 0.f); a2.w = fmaxf(a2.w, 0.f);
  *(float4*)&p2[g][j * 4] = a2;
  __syncthreads();

  // mu: lane j owns output col j
  float am = mub[j];
#pragma unroll 4
  for (int k = 0; k < HID_; ++k) am += muwT[k * IN_ + j] * p2[g][k];
  out[(size_t)(nodebase + g) * IN_ + j] = aug[g][j] + am;
}

extern "C" void kernel_launch(void* const* d_in, const int* in_sizes, int n_in,
                              void* d_out, int out_size, void* d_ws, size_t ws_size,
                              hipStream_t stream) {
  const float* x     = (const float*)d_in[0];
  const float* edges = (const float*)d_in[1];
  const float* w1    = (const float*)d_in[2];
  const float* b1    = (const float*)d_in[3];
  const float* w2    = (const float*)d_in[4];
  const float* b2    = (const float*)d_in[5];
  const float* fc1w  = (const float*)d_in[6];
  const float* fc1b  = (const float*)d_in[7];
  const float* fc2w  = (const float*)d_in[8];
  const float* fc2b  = (const float*)d_in[9];
  const float* muw   = (const float*)d_in[10];
  const float* mub   = (const float*)d_in[11];
  float* out = (float*)d_out;

  float* h1r    = (float*)d_ws;                       // 3*4096*128
  float* h1s    = h1r + 3 * (B_ * V_) * HID_;         // 3*4096*128
  float* aggout = h1s + 3 * (B_ * V_) * HID_;         // 4096*128
  float* fc1wT  = aggout + (B_ * V_) * HID_;          // 160*128
  float* fc2wT  = fc1wT + (IN_ + HID_) * HID_;        // 128*128
  float* muwT   = fc2wT + HID_ * HID_;                // 128*32
  unsigned short* w2f = (unsigned short*)(muwT + HID_ * IN_);  // 3*128*128 bf16

  node_h1<<<2048, 256, 0, stream>>>(x, w1, b1, h1r, h1s);
  weight_prep<<<352, 256, 0, stream>>>(w2, fc1w, fc2w, muw, w2f, fc1wT, fc2wT, muwT);
  edge_mfma<<<dim3(V_, B_), 256, 0, stream>>>(edges, b2, h1r, h1s, w2f, aggout);
  out_mlp<<<512, 256, 0, stream>>>(x, aggout, fc1wT, fc1b, fc2wT, fc2b, muwT, mub, out);
}

// Round 5
// 183.314 us; speedup vs baseline: 1.7707x; 1.0140x over previous
//
#include <hip/hip_runtime.h>
#include <hip/hip_bf16.h>
#include <hip/hip_fp16.h>

#define B_ 64
#define V_ 64
#define E_ 4032
#define HID_ 128
#define IN_ 32
#define BV_ (B_ * V_)

typedef __attribute__((ext_vector_type(2))) _Float16 f16x2;
typedef __attribute__((ext_vector_type(8))) _Float16 f16x8;
typedef __attribute__((ext_vector_type(4))) float f32x4;

__device__ __forceinline__ f16x2 bc2(unsigned u) { return __builtin_bit_cast(f16x2, u); }
__device__ __forceinline__ unsigned bcu(f16x2 h) { return __builtin_bit_cast(unsigned, h); }

// ---------------- Kernel 1: merged prep ----------------
// blocks [0,2048):        h1 halves (f16 out), 2 nodes/block
// blocks [2048,2240):     W2 -> f16 fragment order
// blocks [2240,2400):     fc1wT/fc2wT/muwT transposes
// blocks [2400,6496):     edge-weight gather -> ewT[b][v][tt*64+r]
__global__ void __launch_bounds__(256) prep_all(
    const float* __restrict__ x, const float* __restrict__ w1,
    const float* __restrict__ b1, const float* __restrict__ w2,
    const float* __restrict__ edges, const float* __restrict__ fc1w,
    const float* __restrict__ fc2w, const float* __restrict__ muw,
    _Float16* __restrict__ h1r, _Float16* __restrict__ h1s,
    _Float16* __restrict__ w2f, float* __restrict__ ewT,
    float* __restrict__ fc1wT, float* __restrict__ fc2wT,
    float* __restrict__ muwT) {
  const int bid = blockIdx.x, t = threadIdx.x;

  if (bid < 2048) {  // ---- h1 halves ----
    __shared__ float xs[2][IN_];
    if (t < 64) xs[t >> 5][t & 31] = x[bid * 64 + t];
    __syncthreads();
    const int h = t & 127, half_ = t >> 7;
#pragma unroll
    for (int tt = 0; tt < 3; ++tt) {
      const float* wrow = w1 + ((size_t)((tt + 1) * HID_ + h)) * (2 * IN_) + half_ * IN_;
      float4 w[8];
#pragma unroll
      for (int j = 0; j < 8; ++j) w[j] = ((const float4*)wrow)[j];
      const float bias = half_ ? 0.f : b1[(tt + 1) * HID_ + h];
      _Float16* dst = (half_ ? h1s : h1r) + ((size_t)tt * BV_ + bid * 2) * HID_ + h;
#pragma unroll
      for (int n = 0; n < 2; ++n) {
        float acc = bias;
#pragma unroll
        for (int j = 0; j < 8; ++j)
          acc += w[j].x * xs[n][4 * j] + w[j].y * xs[n][4 * j + 1] +
                 w[j].z * xs[n][4 * j + 2] + w[j].w * xs[n][4 * j + 3];
        dst[n * HID_] = (_Float16)acc;
      }
    }
    return;
  }
  if (bid < 2240) {  // ---- W2 -> f16 fragment order ----
    const int i = (bid - 2048) * 256 + t;  // < 49152
    const int e = i & 7, lane = (i >> 3) & 63, ks = (i >> 9) & 3;
    const int nt = (i >> 11) & 1, w = (i >> 12) & 3, tt = i >> 14;
    const int o = w * 32 + nt * 16 + (lane & 15);
    const int k = ks * 32 + (lane >> 4) * 8 + e;
    w2f[i] = (_Float16)w2[((size_t)((tt + 1) * HID_ + o)) * HID_ + k];
    return;
  }
  if (bid < 2400) {  // ---- transposes ----
    int j = (bid - 2240) * 256 + t;  // < 40960
    if (j < 20480) { fc1wT[j] = fc1w[(j & 127) * (IN_ + HID_) + (j >> 7)]; return; }
    j -= 20480;
    if (j < 16384) { fc2wT[j] = fc2w[(j & 127) * HID_ + (j >> 7)]; return; }
    j -= 16384;
    muwT[j] = muw[(j & 31) * HID_ + (j >> 5)];
    return;
  }
  {  // ---- edge-weight gather ----
    const int g = bid - 2400;  // b*64+v
    if (t < 192) {
      const int b = g >> 6, v = g & 63;
      const int tt = t >> 6, r = t & 63;
      float val = 0.f;
      if (r < 63) {
        const int u = (r < v) ? r : r + 1;
        const int vv = (v > u) ? v - 1 : v;
        val = edges[((size_t)b * E_ + u * 63 + vv) * 4 + tt + 1];
      }
      ewT[(size_t)g * 192 + t] = val;
    }
    return;
  }
}

// ---------------- Kernel 2: per (b,v) edge-MFMA + aggregate (f16) ----------------
// m1: [64][128] f16 rows (256B), XOR swizzle byte^=((r&7)<<4). Build = pure
// packed-f16 (pk_add+pk_max), no conversions. Double-buffered over types.
__global__ void __launch_bounds__(256)
edge_mfma(const float* __restrict__ b2, const _Float16* __restrict__ h1r,
          const _Float16* __restrict__ h1s, const _Float16* __restrict__ w2f,
          const float* __restrict__ ewT, float* __restrict__ aggout) {
  const int v = blockIdx.x, b = blockIdx.y, t = threadIdx.x;
  const int wave = t >> 6, lane = t & 63;
  const int l15 = lane & 15, lg = lane >> 4;
  const int kq = lane & 31, rpar = lane >> 5;

  __shared__ __align__(16) unsigned short m1[2][64 * HID_];
  __shared__ __align__(16) float ews[192];

  if (t < 192) ews[t] = ewT[((size_t)b * V_ + v) * 192 + t];

  // ---- build type 0 into buf 0 ----
  {
    const unsigned short* hrp =
        (const unsigned short*)h1r + ((size_t)b * V_ + v) * HID_ + kq * 4;
    uint2 hru = *(const uint2*)hrp;
    const f16x2 hr0 = bc2(hru.x), hr1 = bc2(hru.y);
#pragma unroll
    for (int j = 0; j < 8; ++j) {
      const int r = wave * 16 + j * 2 + rpar;
      int u = (r < v) ? r : r + 1;
      if (r == 63) u = v;
      uint2 hsu = *(const uint2*)((const unsigned short*)h1s +
                                  ((size_t)b * V_ + u) * HID_ + kq * 4);
      f16x2 o0 = __builtin_elementwise_max(hr0 + bc2(hsu.x), (f16x2)0);
      f16x2 o1 = __builtin_elementwise_max(hr1 + bc2(hsu.y), (f16x2)0);
      uint2 pk = {bcu(o0), bcu(o1)};
      *(uint2*)((char*)m1[0] + r * 256 + ((kq * 8) ^ ((r & 7) << 4))) = pk;
    }
  }

  // ---- B fragments for type 0 (coalesced, reg-resident) ----
  f16x8 bfrag[2][4];
  float b2r[2];
#pragma unroll
  for (int nt = 0; nt < 2; ++nt) {
#pragma unroll
    for (int ks = 0; ks < 4; ++ks)
      bfrag[nt][ks] = *(const f16x8*)(w2f + (((wave * 2 + nt) * 4 + ks) * 64 + lane) * 8);
    b2r[nt] = b2[HID_ + wave * 32 + nt * 16 + l15];
  }

  float acc[4][2][4];
#pragma unroll
  for (int mt = 0; mt < 4; ++mt)
#pragma unroll
    for (int nt = 0; nt < 2; ++nt)
#pragma unroll
      for (int r = 0; r < 4; ++r) acc[mt][nt][r] = 0.f;

  __syncthreads();

#pragma unroll
  for (int tt = 0; tt < 3; ++tt) {
    // prefetch next type's h1 rows (f16, 8B/lane) — overlaps the MFMAs below
    uint2 hrn, hsn[8];
    if (tt < 2) {
      hrn = *(const uint2*)((const unsigned short*)h1r +
                            ((size_t)((tt + 1) * B_ + b) * V_ + v) * HID_ + kq * 4);
#pragma unroll
      for (int j = 0; j < 8; ++j) {
        const int r = wave * 16 + j * 2 + rpar;
        int u = (r < v) ? r : r + 1;
        if (r == 63) u = v;
        hsn[j] = *(const uint2*)((const unsigned short*)h1s +
                                 ((size_t)((tt + 1) * B_ + b) * V_ + u) * HID_ + kq * 4);
      }
    }
    // ---- MFMA on buffer tt&1 ----
    const unsigned short* mb = m1[tt & 1];
#pragma unroll
    for (int mt = 0; mt < 4; ++mt) {
      f16x8 af[4];
#pragma unroll
      for (int ks = 0; ks < 4; ++ks) {
        const int row = mt * 16 + l15;
        af[ks] = *(const f16x8*)((const char*)mb + row * 256 +
                                 ((ks * 64 + lg * 16) ^ ((row & 7) << 4)));
      }
      const float4 ew4 = *(const float4*)&ews[tt * 64 + mt * 16 + lg * 4];
#pragma unroll
      for (int nt = 0; nt < 2; ++nt) {
        f32x4 macc = {0.f, 0.f, 0.f, 0.f};
#pragma unroll
        for (int ks = 0; ks < 4; ++ks)
          macc = __builtin_amdgcn_mfma_f32_16x16x32_f16(af[ks], bfrag[nt][ks], macc, 0, 0, 0);
        acc[mt][nt][0] += fmaxf(macc[0] + b2r[nt], 0.f) * ew4.x;
        acc[mt][nt][1] += fmaxf(macc[1] + b2r[nt], 0.f) * ew4.y;
        acc[mt][nt][2] += fmaxf(macc[2] + b2r[nt], 0.f) * ew4.z;
        acc[mt][nt][3] += fmaxf(macc[3] + b2r[nt], 0.f) * ew4.w;
      }
    }
    // ---- stage next type; reload bfrag ----
    if (tt < 2) {
      const f16x2 hr0 = bc2(hrn.x), hr1 = bc2(hrn.y);
#pragma unroll
      for (int j = 0; j < 8; ++j) {
        const int r = wave * 16 + j * 2 + rpar;
        f16x2 o0 = __builtin_elementwise_max(hr0 + bc2(hsn[j].x), (f16x2)0);
        f16x2 o1 = __builtin_elementwise_max(hr1 + bc2(hsn[j].y), (f16x2)0);
        uint2 pk = {bcu(o0), bcu(o1)};
        *(uint2*)((char*)m1[(tt + 1) & 1] + r * 256 + ((kq * 8) ^ ((r & 7) << 4))) = pk;
      }
#pragma unroll
      for (int nt = 0; nt < 2; ++nt) {
#pragma unroll
        for (int ks = 0; ks < 4; ++ks)
          bfrag[nt][ks] = *(const f16x8*)(
              w2f + (((((tt + 1) * 4 + wave) * 2 + nt) * 4 + ks) * 64 + lane) * 8);
        b2r[nt] = b2[(tt + 2) * HID_ + wave * 32 + nt * 16 + l15];
      }
    }
    __syncthreads();
  }

  // ---- reduce 64 edge rows -> agg[128] ----
#pragma unroll
  for (int nt = 0; nt < 2; ++nt) {
    float s = 0.f;
#pragma unroll
    for (int mt = 0; mt < 4; ++mt)
#pragma unroll
      for (int r = 0; r < 4; ++r) s += acc[mt][nt][r];
    s += __shfl_xor(s, 16);
    s += __shfl_xor(s, 32);
    if (lane < 16)
      aggout[((size_t)b * V_ + v) * HID_ + wave * 32 + nt * 16 + l15] = s;
  }
}

// ---------------- Kernel 3: output MLP (fp32), 8 nodes/block ----------------
// LDS padded to stride 164/132 (≡4 mod 32) -> 8 groups hit distinct banks.
__global__ void __launch_bounds__(256) out_mlp(
    const float* __restrict__ x, const float* __restrict__ aggout,
    const float* __restrict__ fc1wT, const float* __restrict__ fc1b,
    const float* __restrict__ fc2wT, const float* __restrict__ fc2b,
    const float* __restrict__ muwT, const float* __restrict__ mub,
    float* __restrict__ out) {
  const int t = threadIdx.x;
  const int g = t >> 5, j = t & 31;
  const int nodebase = blockIdx.x * 8;
  __shared__ __align__(16) float aug[8][164];
  __shared__ __align__(16) float p1[8][132];
  __shared__ __align__(16) float p2[8][132];

  aug[t >> 5][t & 31] = x[nodebase * IN_ + t];
  {
    float4 a4 = *(const float4*)(aggout + (size_t)nodebase * HID_ + t * 4);
    *(float4*)&aug[t >> 5][IN_ + (t & 31) * 4] = a4;
  }
  __syncthreads();

  float4 a1 = *(const float4*)(fc1b + j * 4);
#pragma unroll 4
  for (int k = 0; k < IN_ + HID_; ++k) {
    float4 w = *(const float4*)(fc1wT + (size_t)k * HID_ + j * 4);
    const float a = aug[g][k];
    a1.x += w.x * a; a1.y += w.y * a; a1.z += w.z * a; a1.w += w.w * a;
  }
  a1.x = fmaxf(a1.x, 0.f); a1.y = fmaxf(a1.y, 0.f);
  a1.z = fmaxf(a1.z, 0.f); a1.w = fmaxf(a1.w, 0.f);
  *(float4*)&p1[g][j * 4] = a1;
  __syncthreads();

  float4 a2 = *(const float4*)(fc2b + j * 4);
#pragma unroll 4
  for (int k = 0; k < HID_; ++k) {
    float4 w = *(const float4*)(fc2wT + (size_t)k * HID_ + j * 4);
    const float a = p1[g][k];
    a2.x += w.x * a; a2.y += w.y * a; a2.z += w.z * a; a2.w += w.w * a;
  }
  a2.x = fmaxf(a2.x, 0.f); a2.y = fmaxf(a2.y, 0.f);
  a2.z = fmaxf(a2.z, 0.f); a2.w = fmaxf(a2.w, 0.f);
  *(float4*)&p2[g][j * 4] = a2;
  __syncthreads();

  float am = mub[j];
#pragma unroll 4
  for (int k = 0; k < HID_; ++k) am += muwT[k * IN_ + j] * p2[g][k];
  out[(size_t)(nodebase + g) * IN_ + j] = aug[g][j] + am;
}

extern "C" void kernel_launch(void* const* d_in, const int* in_sizes, int n_in,
                              void* d_out, int out_size, void* d_ws, size_t ws_size,
                              hipStream_t stream) {
  const float* x     = (const float*)d_in[0];
  const float* edges = (const float*)d_in[1];
  const float* w1    = (const float*)d_in[2];
  const float* b1    = (const float*)d_in[3];
  const float* w2    = (const float*)d_in[4];
  const float* b2    = (const float*)d_in[5];
  const float* fc1w  = (const float*)d_in[6];
  const float* fc1b  = (const float*)d_in[7];
  const float* fc2w  = (const float*)d_in[8];
  const float* fc2b  = (const float*)d_in[9];
  const float* muw   = (const float*)d_in[10];
  const float* mub   = (const float*)d_in[11];
  float* out = (float*)d_out;

  float* aggout = (float*)d_ws;                        // 4096*128 f32
  float* fc1wT  = aggout + BV_ * HID_;                 // 160*128
  float* fc2wT  = fc1wT + (IN_ + HID_) * HID_;         // 128*128
  float* muwT   = fc2wT + HID_ * HID_;                 // 128*32
  float* ewT    = muwT + HID_ * IN_;                   // 4096*192
  _Float16* h1r = (_Float16*)(ewT + (size_t)BV_ * 192);        // 3*4096*128 f16
  _Float16* h1s = h1r + (size_t)3 * BV_ * HID_;                // 3*4096*128 f16
  _Float16* w2f = h1s + (size_t)3 * BV_ * HID_;                // 3*128*128 f16

  prep_all<<<6496, 256, 0, stream>>>(x, w1, b1, w2, edges, fc1w, fc2w, muw,
                                     h1r, h1s, w2f, ewT, fc1wT, fc2wT, muwT);
  edge_mfma<<<dim3(V_, B_), 256, 0, stream>>>(b2, h1r, h1s, w2f, ewT, aggout);
  out_mlp<<<512, 256, 0, stream>>>(x, aggout, fc1wT, fc1b, fc2wT, fc2b, muwT, mub, out);
}